// Round 1
// 84.831 us; speedup vs baseline: 1.0159x; 1.0159x over previous
//
#include <hip/hip_runtime.h>
#include <hip/hip_fp16.h>
#include <math.h>

typedef unsigned long long u64;
typedef unsigned int uint32;

// gumbel from uniform, in double -- fallback path only (logits != 0), matches
// f64 reference decisions bit-exactly
__device__ __forceinline__ double gumbel(double u) {
  u = fmin(fmax(u, 1e-10), 1.0 - 1e-10);
  return -log(-log(u));
}

// r = m[lane] ? tval : fval  -- mask in an SGPR pair, one v_cndmask selects a
// packed half2 (2 batch rows) per lane: 2 cells per instruction.
__device__ __forceinline__ uint32 csel2(u64 m, uint32 tval, uint32 fval) {
  uint32 r;
  asm("v_cndmask_b32 %0, %1, %2, %3" : "=v"(r) : "v"(fval), "v"(tval), "s"(m));
  return r;
}
__device__ __forceinline__ uint32 pkmin(uint32 a, uint32 b) {
  uint32 r;
  asm("v_pk_min_f16 %0, %1, %2" : "=v"(r) : "v"(a), "v"(b));
  return r;
}
__device__ __forceinline__ uint32 pkmax(uint32 a, uint32 b) {
  uint32 r;
  asm("v_pk_max_f16 %0, %1, %2" : "=v"(r) : "v"(a), "v"(b));
  return r;
}

#define ONE2 0x3C003C00u  // packed half2 {1.0, 1.0}

// One wave per (layer, o-group, 4-input chunk). Lane l = output o = g*64+l.
// v2: each thread covers 4 inputs -> 32B contiguous l / 32B contiguous u per
// thread (was 16B at 4KB stride): halves DRAM line over-fetch, halves waves.
// FAST PATH: logits identically zero => argmax(logits+gumbel(u)) == argmax(u)
// (gumbel strictly monotone) -- bit-exact. f64 fallback kept for nonzero
// logits (never taken here).
__global__ __launch_bounds__(256, 4) void masks_kernel(
    const float* __restrict__ l0, const float* __restrict__ u0,
    const float* __restrict__ l1, const float* __restrict__ u1,
    u64* __restrict__ mT0, u64* __restrict__ mT1) {
  int t = blockIdx.x * 256 + threadIdx.x;
  int W = t >> 6;          // wave id, 0..1023
  int lane = t & 63;
  const float* lp;
  const float* up;
  u64* mp;
  int nin, g, i0;          // i0 = first input index of this wave's 4-chunk
  if (W < 512) {           // layer 0: 4 groups x 128 chunks
    g = W >> 7; int c = W & 127;
    lp = l0; up = u0; nin = 512; i0 = c << 2;
    mp = mT0 + (g << 9) + i0;
  } else {                 // layer 1: 8 groups x 64 chunks
    int W1 = W - 512;
    g = W1 >> 6; int c = W1 & 63;
    lp = l1; up = u1; nin = 256; i0 = c << 2;
    mp = mT1 + (g << 8) + i0;
  }
  int o = (g << 6) + lane;
  int idx = (o * nin + i0) << 1;          // (o, i0, e=0), 32B-aligned
  float4 la = *(const float4*)(lp + idx);
  float4 lb = *(const float4*)(lp + idx + 4);
  float4 ua = *(const float4*)(up + idx);
  float4 ub = *(const float4*)(up + idx + 4);
  bool d0, d1, d2, d3;
  bool lz = la.x == 0.0f && la.y == 0.0f && la.z == 0.0f && la.w == 0.0f &&
            lb.x == 0.0f && lb.y == 0.0f && lb.z == 0.0f && lb.w == 0.0f;
  if (lz) {
    d0 = ua.y > ua.x;     // logits zero: raw-uniform compare (monotone-exact)
    d1 = ua.w > ua.z;
    d2 = ub.y > ub.x;
    d3 = ub.w > ub.z;
  } else {
    d0 = ((double)la.y + gumbel((double)ua.y)) > ((double)la.x + gumbel((double)ua.x));
    d1 = ((double)la.w + gumbel((double)ua.w)) > ((double)la.z + gumbel((double)ua.z));
    d2 = ((double)lb.y + gumbel((double)ub.y)) > ((double)lb.x + gumbel((double)ub.x));
    d3 = ((double)lb.w + gumbel((double)ub.w)) > ((double)lb.z + gumbel((double)ub.z));
  }
  u64 m0 = __ballot(d0);
  u64 m1 = __ballot(d1);
  u64 m2 = __ballot(d2);
  u64 m3 = __ballot(d3);
  if (lane == 0) {
    ulonglong2 v0; v0.x = m0; v0.y = m1;
    ulonglong2 v1; v1.x = m2; v1.y = m3;
    *(ulonglong2*)mp = v0;        // two 16B stores, 32B contiguous
    *(ulonglong2*)(mp + 2) = v1;
  }
}

// One block per ROW PAIR (b0=2*bid, b1=b0+1), cells packed as half2 {b0,b1}.
// Phase 1: h[o] = min over selected x (split-K by 2 waves/group).
// Phase 2: out[o] = max over selected h. h lives only in LDS (f16, so phase 2
// adds no rounding error beyond the single f16 quantization of x: <=2^-12).
// launch_bounds min-waves/EU relaxed 8->4: grid residency is 2 blocks/CU
// (= 4 waves/EU) anyway; the old bound capped VGPRs at 64 for an unroll-8
// body (spill risk) with zero occupancy benefit.
__global__ __launch_bounds__(512, 4) void fused_kernel(
    const float* __restrict__ x, const u64* __restrict__ mT0,
    const u64* __restrict__ mT1, float* __restrict__ out) {
  __shared__ uint32 sxp[512];       // packed half2 x for both rows
  __shared__ uint32 shp[256];       // packed half2 h
  __shared__ uint32 spart[8][64];
  const int tid = threadIdx.x;
  const int b0 = blockIdx.x * 2;
  {
    float f0 = x[b0 * 512 + tid];
    float f1 = x[b0 * 512 + 512 + tid];
    __half2 p = __floats2half2_rn(f0, f1);   // RNE: err <= 2^-12
    sxp[tid] = *(uint32*)&p;
  }
  __syncthreads();
  const int w = __builtin_amdgcn_readfirstlane(tid >> 6);  // wave-uniform
  const int lane = tid & 63;

  // ---- phase 1: layer 0 (min over selected x, else 1.0) ----
  {
    int g = w >> 1, half = w & 1;
    const u64* __restrict__ mrow = mT0 + (g << 9) + (half << 8);
    const uint32* xs = sxp + (half << 8);
    uint32 acc0 = ONE2, acc1 = ONE2;
#pragma unroll 8
    for (int i = 0; i < 256; i += 4) {
      uint4 xv = *(const uint4*)(xs + i);       // ds_read_b128 broadcast: 4i x 2rows
      u64 m0 = mrow[i], m1 = mrow[i + 1];
      u64 m2 = mrow[i + 2], m3 = mrow[i + 3];
      uint32 t0 = csel2(m0, xv.x, ONE2);
      uint32 t1 = csel2(m1, xv.y, ONE2);
      uint32 t2 = csel2(m2, xv.z, ONE2);
      uint32 t3 = csel2(m3, xv.w, ONE2);
      acc0 = pkmin(acc0, pkmin(t0, t1));        // chain 0
      acc1 = pkmin(acc1, pkmin(t2, t3));        // chain 1
    }
    spart[w][lane] = pkmin(acc0, acc1);
  }
  __syncthreads();
  if (w < 4) shp[(w << 6) + lane] = pkmin(spart[2 * w][lane], spart[2 * w + 1][lane]);
  __syncthreads();

  // ---- phase 2: layer 1 (max over selected h, else 0.0) ----
  {
    const u64* __restrict__ mrow = mT1 + (w << 8);
    uint32 acc0 = 0u, acc1 = 0u;                // packed half2 {0,0}
#pragma unroll 8
    for (int i = 0; i < 256; i += 4) {
      uint4 hv = *(const uint4*)(shp + i);      // ds_read_b128 broadcast
      u64 m0 = mrow[i], m1 = mrow[i + 1];
      u64 m2 = mrow[i + 2], m3 = mrow[i + 3];
      uint32 t0 = csel2(m0, hv.x, 0u);
      uint32 t1 = csel2(m1, hv.y, 0u);
      uint32 t2 = csel2(m2, hv.z, 0u);
      uint32 t3 = csel2(m3, hv.w, 0u);
      acc0 = pkmax(acc0, pkmax(t0, t1));        // chain 0
      acc1 = pkmax(acc1, pkmax(t2, t3));        // chain 1
    }
    uint32 acc = pkmax(acc0, acc1);
    __half2 hh = *(__half2*)&acc;
    int o = (w << 6) + lane;
    out[b0 * 512 + o]       = __low2float(hh);   // row b0
    out[b0 * 512 + 512 + o] = __high2float(hh);  // row b1
  }
}

extern "C" void kernel_launch(void* const* d_in, const int* in_sizes, int n_in,
                              void* d_out, int out_size, void* d_ws, size_t ws_size,
                              hipStream_t stream) {
  const float* x  = (const float*)d_in[0];
  const float* l0 = (const float*)d_in[1];
  const float* u0 = (const float*)d_in[2];
  const float* l1 = (const float*)d_in[3];
  const float* u1 = (const float*)d_in[4];
  u64* mT0 = (u64*)d_ws;        // 2048 words, 16 KB
  u64* mT1 = mT0 + 2048;        // 2048 words, 16 KB
  float* out = (float*)d_out;

  hipLaunchKernelGGL(masks_kernel, dim3(256), dim3(256), 0, stream,
                     l0, u0, l1, u1, mT0, mT1);
  hipLaunchKernelGGL(fused_kernel, dim3(512), dim3(512), 0, stream,
                     x, mT0, mT1, out);
}